// Round 6
// baseline (133.872 us; speedup 1.0000x reference)
//
#include <hip/hip_runtime.h>

#define ALPHA 0.2f
constexpr int B_   = 64;
constexpr int N_   = 2048;
constexpr int IN_  = 1024;
constexpr int OUT_ = 1024;
constexpr int CHUNK = 256;            // rows per workgroup in main pass
constexpr int NCH   = N_ / CHUNK;     // 8 chunks per batch
constexpr int WAVES = 8;              // waves per kMain block (512 threads)
constexpr int RPW   = CHUNK / WAVES;  // 32 rows per wave, stride WAVES

// ---- workspace layout (float offsets), ~3.4 MB total ----
constexpr size_t WA2   = 0;        // 1024   : W^T a2 (reduced)
constexpr size_t E0P   = 1024;     // 256    : per-(b,quarter) e0 partials
constexpr size_t ZPART = 1280;     // 512    : B*NCH
constexpr size_t PART1 = 2048;     // 128*1024 partials for W^T a1
constexpr size_t PART2 = 133120;   // 128*1024 partials for W^T a2
constexpr size_t GPART = 264192;   // B*NCH*IN = 524288
constexpr size_t GV    = 788480;   // B*IN = 65536

__device__ inline float wave_reduce_sum(float v) {
    #pragma unroll
    for (int off = 32; off > 0; off >>= 1) v += __shfl_xor(v, off);
    return v;
}

// Partial wa1/wa2: block owns 8 rows of W, threads cover all 1024 cols (float4).
__global__ void kW(const float* __restrict__ W, const float* __restrict__ aw,
                   float* __restrict__ ws) {
    int t = threadIdx.x, blk = blockIdx.x;   // 128 blocks
    float4 acc1 = make_float4(0.f, 0.f, 0.f, 0.f);
    float4 acc2 = make_float4(0.f, 0.f, 0.f, 0.f);
    #pragma unroll
    for (int r = 0; r < 8; ++r) {
        int d = blk * 8 + r;
        float a1 = aw[d], a2 = aw[OUT_ + d];
        float4 w = ((const float4*)(W + (size_t)d * IN_))[t];
        acc1.x += a1 * w.x; acc1.y += a1 * w.y; acc1.z += a1 * w.z; acc1.w += a1 * w.w;
        acc2.x += a2 * w.x; acc2.y += a2 * w.y; acc2.z += a2 * w.z; acc2.w += a2 * w.w;
    }
    ((float4*)(ws + PART1))[blk * 256 + t] = acc1;
    ((float4*)(ws + PART2))[blk * 256 + t] = acc2;
}

// Blocks 0..3   : reduce 128 PART2 partials -> WA2 (1024 cols).
// Blocks 4..259 : idx=(b,q): E0P[b*4+q] = sum_{col in quarter q} f[b,0,col]*
//                 (sum_r PART1[r,col]) + wb[col]*(a1[col]+a2[col])
__global__ void kS(const float* __restrict__ f, const float* __restrict__ wb,
                   const float* __restrict__ aw, float* __restrict__ ws) {
    int t = threadIdx.x;
    if (blockIdx.x < 4) {
        int col = blockIdx.x * 256 + t;
        const float* p = ws + PART2 + col;
        float s = 0.f;
        #pragma unroll 8
        for (int r = 0; r < 128; ++r) s += p[(size_t)r * 1024];
        ws[WA2 + col] = s;
    } else {
        int idx = blockIdx.x - 4;           // 0..255
        int b = idx >> 2, q = idx & 3;
        int col = q * 256 + t;
        const float* p = ws + PART1 + col;
        float ps = 0.f;
        #pragma unroll 8
        for (int r = 0; r < 128; ++r) ps += p[(size_t)r * 1024];
        float acc = f[(size_t)b * N_ * IN_ + col] * ps
                  + wb[col] * (aw[col] + aw[OUT_ + col]);
        __shared__ float red[256];
        red[t] = acc;
        __syncthreads();
        for (int off = 128; off > 0; off >>= 1) {
            if (t < off) red[t] += red[t + off];
            __syncthreads();
        }
        if (t == 0) ws[E0P + idx] = red[0];
    }
}

// Single feature pass, 8 waves/block, depth-2 row pipeline.
// Per row n: s=f.wa2, w=exp(leaky(e0+s+ab)); gpart += w*f; zpart += w.
__global__ void __launch_bounds__(512, 4)
kMain(const float* __restrict__ f, const float* __restrict__ ab,
      float* __restrict__ ws) {
    int b = blockIdx.y, chunk = blockIdx.x;
    int t = threadIdx.x, wave = t >> 6, lane = t & 63;
    float cst = ws[E0P + b * 4] + ws[E0P + b * 4 + 1]
              + ws[E0P + b * 4 + 2] + ws[E0P + b * 4 + 3] + ab[0];

    const float4* wa2_4 = (const float4*)(ws + WA2);
    float4 ra2[4];
    #pragma unroll
    for (int k = 0; k < 4; ++k) ra2[k] = wa2_4[k * 64 + lane];

    // fb4[j*2048 + k*64] = row (wave + j*8), float4-lane slot k
    const float4* fb4 = (const float4*)(f + ((size_t)b * N_ + (size_t)chunk * CHUNK) * IN_)
                        + (size_t)wave * 256 + lane;

    float4 acc[4];
    #pragma unroll
    for (int k = 0; k < 4; ++k) acc[k] = make_float4(0.f, 0.f, 0.f, 0.f);
    float z = 0.f;

    float4 va[4], vb_[4], vc[4], vd[4];

    #define LOADROW(V, J)                                              \
        { _Pragma("unroll")                                            \
          for (int k = 0; k < 4; ++k) V[k] = fb4[(size_t)(J) * 2048 + k * 64]; }

    #define PROC(V)                                                    \
        { float d0 = V[0].x*ra2[0].x + V[0].y*ra2[0].y + V[0].z*ra2[0].z + V[0].w*ra2[0].w; \
          float d1 = V[1].x*ra2[1].x + V[1].y*ra2[1].y + V[1].z*ra2[1].z + V[1].w*ra2[1].w; \
          float d2 = V[2].x*ra2[2].x + V[2].y*ra2[2].y + V[2].z*ra2[2].z + V[2].w*ra2[2].w; \
          float d3 = V[3].x*ra2[3].x + V[3].y*ra2[3].y + V[3].z*ra2[3].z + V[3].w*ra2[3].w; \
          float dt = (d0 + d1) + (d2 + d3);                            \
          dt = wave_reduce_sum(dt);                                    \
          float e = dt + cst;                                          \
          e = e >= 0.f ? e : ALPHA * e;                                \
          float w = __expf(e);                                         \
          z += w;                                                      \
          _Pragma("unroll")                                            \
          for (int k = 0; k < 4; ++k) {                                \
              acc[k].x += w * V[k].x; acc[k].y += w * V[k].y;          \
              acc[k].z += w * V[k].z; acc[k].w += w * V[k].w;          \
          } }

    LOADROW(va, 0);
    LOADROW(vb_, 1);
    for (int j = 0; j + 2 < RPW; j += 2) {
        LOADROW(vc, j + 2);
        PROC(va);
        LOADROW(vd, j + 3);
        PROC(vb_);
        #pragma unroll
        for (int k = 0; k < 4; ++k) { va[k] = vc[k]; vb_[k] = vd[k]; }
    }
    PROC(va);
    PROC(vb_);
    #undef LOADROW
    #undef PROC

    __shared__ float4 gbuf[WAVES][256];
    __shared__ float  zbuf[WAVES];
    #pragma unroll
    for (int k = 0; k < 4; ++k) gbuf[wave][k * 64 + lane] = acc[k];
    if (lane == 0) zbuf[wave] = z;
    __syncthreads();
    if (t < 256) {
        float4 s = gbuf[0][t];
        #pragma unroll
        for (int w = 1; w < WAVES; ++w) {
            float4 u = gbuf[w][t];
            s.x += u.x; s.y += u.y; s.z += u.z; s.w += u.w;
        }
        ((float4*)(ws + GPART))[((size_t)b * NCH + chunk) * 256 + t] = s;
        if (t == 0) {
            float zz = zbuf[0];
            #pragma unroll
            for (int w = 1; w < WAVES; ++w) zz += zbuf[w];
            ws[ZPART + b * NCH + chunk] = zz;
        }
    }
}

// g[b,:] = (sum_c gpart[b,c,:]) / (sum_c zpart[b,c])
__global__ void kE(float* __restrict__ ws) {
    int b = blockIdx.x, t = threadIdx.x;
    __shared__ float zinv;
    if (t == 0) {
        float zz = 0.f;
        #pragma unroll
        for (int c = 0; c < NCH; ++c) zz += ws[ZPART + b * NCH + c];
        zinv = 1.0f / zz;
    }
    __syncthreads();
    const float4* gp = (const float4*)(ws + GPART);
    float4 acc = make_float4(0.f, 0.f, 0.f, 0.f);
    #pragma unroll
    for (int c = 0; c < NCH; ++c) {
        float4 v = gp[((size_t)b * NCH + c) * 256 + t];
        acc.x += v.x; acc.y += v.y; acc.z += v.z; acc.w += v.w;
    }
    acc.x *= zinv; acc.y *= zinv; acc.z *= zinv; acc.w *= zinv;
    ((float4*)(ws + GV))[b * 256 + t] = acc;
}

// out[b,d] = relu( g[b,:].W[d,:] + w_b[d] + bias_out[d] )
// grid(256,2): block = (4 d's, 32 b's). W rows in registers; g from L2.
__global__ void kF(const float* __restrict__ W, const float* __restrict__ wb,
                   const float* __restrict__ bias, const float* __restrict__ ws,
                   float* __restrict__ out) {
    int t = threadIdx.x, wave = t >> 6, lane = t & 63;
    int d  = blockIdx.x * 4 + wave;
    int b0 = blockIdx.y * 32;
    const float4* w4 = (const float4*)(W + (size_t)d * IN_);
    float4 wreg[4];
    #pragma unroll
    for (int k = 0; k < 4; ++k) wreg[k] = w4[k * 64 + lane];
    float wbb = wb[d] + bias[d];
    const float4* gv = (const float4*)(ws + GV);
    #pragma unroll 4
    for (int bi = 0; bi < 32; ++bi) {
        int b = b0 + bi;
        float acc = 0.f;
        #pragma unroll
        for (int k = 0; k < 4; ++k) {
            float4 g = gv[b * 256 + k * 64 + lane];
            acc += g.x * wreg[k].x + g.y * wreg[k].y + g.z * wreg[k].z + g.w * wreg[k].w;
        }
        acc = wave_reduce_sum(acc);
        if (lane == 0) {
            float p = acc + wbb;
            out[(size_t)b * OUT_ + d] = p > 0.f ? p : 0.f;
        }
    }
}

extern "C" void kernel_launch(void* const* d_in, const int* in_sizes, int n_in,
                              void* d_out, int out_size, void* d_ws, size_t ws_size,
                              hipStream_t stream) {
    const float* f    = (const float*)d_in[0];  // (64,2048,1024)
    const float* W    = (const float*)d_in[1];  // (1024,1024)
    const float* wb   = (const float*)d_in[2];  // (1024,)
    const float* aw   = (const float*)d_in[3];  // (2048,)
    const float* ab   = (const float*)d_in[4];  // scalar
    const float* bias = (const float*)d_in[5];  // (1024,)
    float* out = (float*)d_out;                 // (64,1,1024) f32
    float* ws  = (float*)d_ws;

    kW   <<<dim3(128), 256, 0, stream>>>(W, aw, ws);
    kS   <<<dim3(4 + 256), 256, 0, stream>>>(f, wb, aw, ws);
    kMain<<<dim3(NCH, B_), 512, 0, stream>>>(f, ab, ws);
    kE   <<<dim3(B_), 256, 0, stream>>>(ws);
    kF   <<<dim3(OUT_ / 4, 2), 256, 0, stream>>>(W, wb, bias, ws, out);
}

// Round 7
// 122.172 us; speedup vs baseline: 1.0958x; 1.0958x over previous
//
#include <hip/hip_runtime.h>

#define ALPHA 0.2f
constexpr int B_   = 64;
constexpr int N_   = 2048;
constexpr int IN_  = 1024;
constexpr int OUT_ = 1024;
constexpr int CHUNK = 256;            // rows per workgroup in main pass (R4-proven)
constexpr int NCH   = N_ / CHUNK;     // 8 chunks per batch
constexpr int RPW   = CHUNK / 4;      // 64 rows per wave (4 waves/block)

// ---- workspace layout (float offsets), ~2.4 MB total ----
constexpr size_t WA2   = 0;        // 1024   : W^T a2
constexpr size_t E0P   = 1024;     // 64*64  : e0 partials [slab][b]
constexpr size_t ZPART = 5120;     // 512    : B*NCH
constexpr size_t GPART = 8192;     // B*NCH*IN = 524288
constexpr size_t GV    = 532480;   // B*IN = 65536

__device__ inline float wave_reduce_sum(float v) {
    #pragma unroll
    for (int off = 32; off > 0; off >>= 1) v += __shfl_xor(v, off);
    return v;
}

// Fused prologue, no cross-block reduction. Block s owns cols [s*16, s*16+16):
//   wa2[cols]          = sum_d W[d,col] * a2[d]          (written to ws)
//   e0p[s][b]          = sum_{col in slab} f[b,0,col] * wa1_local[col]
//                        + sum_{col in slab} wb[col]*(a1[col]+a2[col])
// kMain sums e0p over s.
__global__ void kPre(const float* __restrict__ W, const float* __restrict__ f,
                     const float* __restrict__ wb, const float* __restrict__ aw,
                     float* __restrict__ ws) {
    int s = blockIdx.x;          // 64 slabs
    int t = threadIdx.x;         // 256
    int c  = t & 15;             // col within slab
    int rg = t >> 4;             // 16 row-groups of 64 rows
    int col = s * 16 + c;
    float a1acc = 0.f, a2acc = 0.f;
    for (int i = 0; i < 64; ++i) {
        int d = rg * 64 + i;
        float w = W[(size_t)d * IN_ + col];
        a1acc += aw[d] * w;
        a2acc += aw[OUT_ + d] * w;
    }
    __shared__ float s1[16][16], s2[16][16];
    __shared__ float wa1L[16];
    __shared__ float wbshare_s;
    s1[rg][c] = a1acc;
    s2[rg][c] = a2acc;
    __syncthreads();
    if (t < 16) {
        float x1 = 0.f, x2 = 0.f;
        #pragma unroll
        for (int r = 0; r < 16; ++r) { x1 += s1[r][t]; x2 += s2[r][t]; }
        wa1L[t] = x1;
        ws[WA2 + s * 16 + t] = x2;
    }
    if (t == 0) {
        float x = 0.f;
        #pragma unroll
        for (int c2 = 0; c2 < 16; ++c2) {
            int cc = s * 16 + c2;
            x += wb[cc] * (aw[cc] + aw[OUT_ + cc]);
        }
        wbshare_s = x;
    }
    __syncthreads();
    // e0 partials: thread -> (b = t>>2, q = t&3), 4 lanes per b
    int b = t >> 2, q = t & 3;
    float4 fv = ((const float4*)(f + (size_t)b * N_ * IN_ + s * 16))[q];
    float4 w1 = ((const float4*)wa1L)[q];
    float dotv = fv.x * w1.x + fv.y * w1.y + fv.z * w1.z + fv.w * w1.w;
    dotv += __shfl_xor(dotv, 1);
    dotv += __shfl_xor(dotv, 2);
    if (q == 0) ws[E0P + s * 64 + b] = dotv + wbshare_s;
}

// Single feature pass (R4-proven body): per row n, s=f.wa2, w=exp(leaky(e0+s+ab)),
// accumulate gpart += w*f and zpart += w.   Wave-per-row, reg double-buffer.
__global__ void kMain(const float* __restrict__ f, const float* __restrict__ ab,
                      float* __restrict__ ws) {
    int b = blockIdx.y, chunk = blockIdx.x;
    int t = threadIdx.x, wave = t >> 6, lane = t & 63;

    __shared__ float cstS;
    if (t < 64) {
        float v = ws[E0P + (size_t)t * 64 + b];
        v = wave_reduce_sum(v);
        if (t == 0) cstS = v + ab[0];
    }
    __syncthreads();
    float cst = cstS;

    const float4* wa2_4 = (const float4*)(ws + WA2);
    float4 ra2[4];
    #pragma unroll
    for (int k = 0; k < 4; ++k) ra2[k] = wa2_4[k * 64 + lane];

    const float4* fbase = (const float4*)(f + ((size_t)b * N_ + (size_t)chunk * CHUNK) * IN_);
    float4 acc[4];
    #pragma unroll
    for (int k = 0; k < 4; ++k) acc[k] = make_float4(0.f, 0.f, 0.f, 0.f);
    float z = 0.f;

    float4 v[4], nv[4];
    int r = wave;
    #pragma unroll
    for (int k = 0; k < 4; ++k) v[k] = fbase[(size_t)r * 256 + k * 64 + lane];

    for (int i = 0; i < RPW; ++i) {
        int rn = r + 4;
        if (i + 1 < RPW) {
            #pragma unroll
            for (int k = 0; k < 4; ++k) nv[k] = fbase[(size_t)rn * 256 + k * 64 + lane];
        }
        float dot = 0.f;
        #pragma unroll
        for (int k = 0; k < 4; ++k)
            dot += v[k].x * ra2[k].x + v[k].y * ra2[k].y + v[k].z * ra2[k].z + v[k].w * ra2[k].w;
        dot = wave_reduce_sum(dot);
        float e = dot + cst;
        e = e >= 0.f ? e : ALPHA * e;
        float w = __expf(e);
        z += w;
        #pragma unroll
        for (int k = 0; k < 4; ++k) {
            acc[k].x += w * v[k].x; acc[k].y += w * v[k].y;
            acc[k].z += w * v[k].z; acc[k].w += w * v[k].w;
        }
        if (i + 1 < RPW) {
            #pragma unroll
            for (int k = 0; k < 4; ++k) v[k] = nv[k];
        }
        r = rn;
    }

    __shared__ float4 gbuf[4][256];
    __shared__ float  zbuf[4];
    #pragma unroll
    for (int k = 0; k < 4; ++k) gbuf[wave][k * 64 + lane] = acc[k];
    if (lane == 0) zbuf[wave] = z;
    __syncthreads();
    float4 s0 = gbuf[0][t], s1 = gbuf[1][t], s2 = gbuf[2][t], s3 = gbuf[3][t];
    float4 s = make_float4(s0.x + s1.x + s2.x + s3.x, s0.y + s1.y + s2.y + s3.y,
                           s0.z + s1.z + s2.z + s3.z, s0.w + s1.w + s2.w + s3.w);
    ((float4*)(ws + GPART))[((size_t)b * NCH + chunk) * 256 + t] = s;
    if (t == 0) ws[ZPART + b * NCH + chunk] = zbuf[0] + zbuf[1] + zbuf[2] + zbuf[3];
}

// g[b,:] = (sum_c gpart[b,c,:]) / (sum_c zpart[b,c])
__global__ void kE(float* __restrict__ ws) {
    int b = blockIdx.x, t = threadIdx.x;
    __shared__ float zinv;
    if (t == 0) {
        float zz = 0.f;
        #pragma unroll
        for (int c = 0; c < NCH; ++c) zz += ws[ZPART + b * NCH + c];
        zinv = 1.0f / zz;
    }
    __syncthreads();
    const float4* gp = (const float4*)(ws + GPART);
    float4 acc = make_float4(0.f, 0.f, 0.f, 0.f);
    #pragma unroll
    for (int c = 0; c < NCH; ++c) {
        float4 v = gp[((size_t)b * NCH + c) * 256 + t];
        acc.x += v.x; acc.y += v.y; acc.z += v.z; acc.w += v.w;
    }
    acc.x *= zinv; acc.y *= zinv; acc.z *= zinv; acc.w *= zinv;
    ((float4*)(ws + GV))[b * 256 + t] = acc;
}

// out[b,d] = relu( g[b,:].W[d,:] + w_b[d] + bias_out[d] )
// grid(256,2): block = (4 d's, 32 b's). W rows in registers; g from L2.
__global__ void kF(const float* __restrict__ W, const float* __restrict__ wb,
                   const float* __restrict__ bias, const float* __restrict__ ws,
                   float* __restrict__ out) {
    int t = threadIdx.x, wave = t >> 6, lane = t & 63;
    int d  = blockIdx.x * 4 + wave;
    int b0 = blockIdx.y * 32;
    const float4* w4 = (const float4*)(W + (size_t)d * IN_);
    float4 wreg[4];
    #pragma unroll
    for (int k = 0; k < 4; ++k) wreg[k] = w4[k * 64 + lane];
    float wbb = wb[d] + bias[d];
    const float4* gv = (const float4*)(ws + GV);
    #pragma unroll 4
    for (int bi = 0; bi < 32; ++bi) {
        int b = b0 + bi;
        float acc = 0.f;
        #pragma unroll
        for (int k = 0; k < 4; ++k) {
            float4 g = gv[b * 256 + k * 64 + lane];
            acc += g.x * wreg[k].x + g.y * wreg[k].y + g.z * wreg[k].z + g.w * wreg[k].w;
        }
        acc = wave_reduce_sum(acc);
        if (lane == 0) {
            float p = acc + wbb;
            out[(size_t)b * OUT_ + d] = p > 0.f ? p : 0.f;
        }
    }
}

extern "C" void kernel_launch(void* const* d_in, const int* in_sizes, int n_in,
                              void* d_out, int out_size, void* d_ws, size_t ws_size,
                              hipStream_t stream) {
    const float* f    = (const float*)d_in[0];  // (64,2048,1024)
    const float* W    = (const float*)d_in[1];  // (1024,1024)
    const float* wb   = (const float*)d_in[2];  // (1024,)
    const float* aw   = (const float*)d_in[3];  // (2048,)
    const float* ab   = (const float*)d_in[4];  // scalar
    const float* bias = (const float*)d_in[5];  // (1024,)
    float* out = (float*)d_out;                 // (64,1,1024) f32
    float* ws  = (float*)d_ws;

    kPre <<<dim3(64), 256, 0, stream>>>(W, f, wb, aw, ws);
    kMain<<<dim3(NCH, B_), 256, 0, stream>>>(f, ab, ws);
    kE   <<<dim3(B_), 256, 0, stream>>>(ws);
    kF   <<<dim3(OUT_ / 4, 2), 256, 0, stream>>>(W, wb, bias, ws, out);
}